// Round 10
// baseline (82.115 us; speedup 1.0000x reference)
//
#include <hip/hip_runtime.h>
#include <cstdint>

#define NB 8
#define NBOX 8732
#define NCL 21
#define NCM1 20
#define LASTD 102
#define CONF_TH 0.5f
#define IOU_TH 0.45f
#define TOPK 200
#define MAXOUT 400     // reference row pitch (flat tie-break encoding)
#define SELCAP 200     // provably sufficient accept cap (== TOPK)
#define EMITN 256      // topk reads within-class ranks [0,256) only
#define NTASK (NB * NCM1)
#define THREADS 1024
#define NW 16
#define NIT 9          // ceil(8732/1024)
#define NBIN 2048
#define KPAD 8768      // 64*137 >= NBOX: counting-sorted keys always fit
#define NBATCH (KPAD / 64)

// Exact equivalence (proven): uni>0 && RN_f32(inter/uni) > 0.45f
//   <=>  (double)inter > MIDD*(double)uni   for our operand domain.
// MIDD = double(0.45f) + 2^-26 (midpoint above 0.45f; 0.45f mantissa even so
// midpoint rounds to 0.45f, not >). 25-bit x 24-bit f64 product is exact.
// uni>0 guard removable: no division; valid-valid pairs have uni>=max area>0;
// pairs with a zero (invalid) box give inter==0 -> false. No NaN path.
#define MIDD ((double)IOU_TH + 0x1p-26)

struct SM {
    float4 selbox[SELCAP];        // 3.2 KB
    float4 cbox[2][64];           // 4 KB (staged next-batch candidate boxes)
    float selA[SELCAP];           // 0.8 KB
    float carea[2][64];           // 0.5 KB
    uint64_t selkey[SELCAP];      // 1.6 KB
    uint64_t keys[KPAD];          // 70.1 KB
    unsigned long long supW[2][NW];  // per-wave full-check ballots (slot 0 unused)
    int hist[NBIN];               // 8 KB
    int binstart[NBIN];           // 8 KB
    int wavetot[NW];
    int Mshare, nselshare, prevNshare, doneflag;
};  // ~97 KB

// IoU(>0.45): explicit RN ops + exact f64-product compare, bit-matching the
// host fp32 reference. Symmetric in (a,b).
__device__ __forceinline__ int iou_sup(float4 a, float aA, float4 b, float bA) {
    float x1 = fmaxf(a.x, b.x), y1 = fmaxf(a.y, b.y);
    float x2 = fminf(a.z, b.z), y2 = fminf(a.w, b.w);
    float iw = fmaxf(__fsub_rn(x2, x1), 0.0f);
    float ih = fmaxf(__fsub_rn(y2, y1), 0.0f);
    float inter = __fmul_rn(iw, ih);
    float uni = __fsub_rn(__fadd_rn(aA, bA), inter);
    return (double)inter > MIDD * (double)uni;
}

__device__ __forceinline__ float4 load_box(const float* __restrict__ img,
                                           int boxoff, uint64_t key) {
    if ((key >> 32) == 0) return make_float4(0.f, 0.f, 0.f, 0.f);
    uint32_t i = 0xFFFFFFFFu - (uint32_t)key;
    const float* bp = img + (size_t)i * LASTD + boxoff;
    return make_float4(bp[0], bp[1], bp[2], bp[3]);
}

__device__ __forceinline__ float box_area(float4 b) {
    return __fmul_rn(__fsub_rn(b.z, b.x), __fsub_rn(b.w, b.y));
}

// One block per (image, class): 2048-bin counting sort of all conf>0.5
// candidates into exact (score desc, idx asc) order, then a one-barrier-per-
// batch pipelined greedy scan. Wave0 {delta-check + resolve with ON-DEMAND
// victim masks (one wave-wide IoU per accept)} overlaps waves 1-15 {chunked
// early-exit full-check of next batch + staging}. Exactly replicates the
// reference argmax+suppress loop; SELCAP=200 is output-equivalent (r7 proof).
__global__ __launch_bounds__(THREADS) void nms_per_class(const float* __restrict__ yp,
                                                         float* __restrict__ rows) {
    __shared__ SM sm;
    const int task = blockIdx.x;
    const int b = task / NCM1;
    const int cm1 = task % NCM1;
    const int tid = threadIdx.x;
    const int lane = tid & 63;
    const int wav = tid >> 6;
    const float* img = yp + (size_t)b * NBOX * LASTD;
    const int boxoff = NCL + 4 * cm1;

    // ---- phase 1: conf column loads (all 9 in flight) ----
    float confs[NIT];
    #pragma unroll
    for (int it = 0; it < NIT; ++it) {
        int idx = it * THREADS + tid;
        confs[it] = (idx < NBOX) ? img[(size_t)idx * LASTD + (1 + cm1)] : 0.0f;
    }
    sm.hist[tid] = 0; sm.hist[tid + THREADS] = 0;
    __syncthreads();

    // ---- phase 2: 2048-bin histogram (top 11 mantissa bits, conf in (0.5,1)) --
    #pragma unroll
    for (int it = 0; it < NIT; ++it) {
        int idx = it * THREADS + tid;
        if (idx < NBOX && confs[it] > CONF_TH) {
            int bin = (int)((__float_as_uint(confs[it]) - 0x3F000000u) >> 12);
            atomicAdd(&sm.hist[bin], 1);
        }
    }
    __syncthreads();

    // ---- phase 3: descending bin bases via suffix-sum over bin pairs ----
    int h0 = sm.hist[2 * tid], h1 = sm.hist[2 * tid + 1];
    int x = h0 + h1;
    int s = x;
    #pragma unroll
    for (int d = 1; d <= 32; d <<= 1) {
        int y = __shfl_down(s, d);
        if (lane + d < 64) s += y;
    }
    if (lane == 0) sm.wavetot[wav] = s;
    __syncthreads();
    int cross = 0;
    #pragma unroll
    for (int w = 0; w < NW; ++w)
        if (w > wav) cross += sm.wavetot[w];
    int Safter = cross + s - x;               // keys in bins strictly above
    sm.binstart[2 * tid + 1] = Safter;        // higher bin (higher score) first
    sm.binstart[2 * tid] = Safter + h1;
    if (tid == 0) sm.Mshare = cross + s;
    sm.hist[2 * tid] = 0; sm.hist[2 * tid + 1] = 0;  // reuse as scatter ctr
    __syncthreads();

    // ---- phase 4: scatter keys to bin regions ----
    #pragma unroll
    for (int it = 0; it < NIT; ++it) {
        int idx = it * THREADS + tid;
        if (idx < NBOX && confs[it] > CONF_TH) {
            uint32_t bits = __float_as_uint(confs[it]);
            int bin = (int)((bits - 0x3F000000u) >> 12);
            int slot = sm.binstart[bin] + atomicAdd(&sm.hist[bin], 1);
            sm.keys[slot] = ((uint64_t)bits << 32) |
                            (uint32_t)(0xFFFFFFFFu - (uint32_t)idx);
        }
    }
    __syncthreads();
    const int M = sm.Mshare;
    for (int m = M + tid; m < KPAD; m += THREADS) sm.keys[m] = 0;
    // ---- phase 5: per-bin insertion sort (2 bins/thread, ~2 keys/bin) ----
    for (int f = tid; f < NBIN; f += THREADS) {
        int s0 = sm.binstart[f], h = sm.hist[f];
        for (int i2 = 1; i2 < h; ++i2) {
            uint64_t key = sm.keys[s0 + i2];
            int j = i2 - 1;
            while (j >= 0 && sm.keys[s0 + j] < key) {
                sm.keys[s0 + j + 1] = sm.keys[s0 + j];
                --j;
            }
            sm.keys[s0 + j + 1] = key;
        }
    }
    __syncthreads();

    // ---- phase 6: one-barrier-per-batch pipelined greedy scan ----
    uint64_t keyC = sm.keys[lane];
    uint64_t keyN = sm.keys[64 + lane];
    float4 boxC = load_box(img, boxoff, keyC);
    float4 boxN = load_box(img, boxoff, keyN);
    float aC = box_area(boxC), aN = box_area(boxN);
    // prologue: stage cbox[1]=batch1, zero supW
    if (wav == 1) { sm.cbox[1][lane] = boxN; sm.carea[1][lane] = aN; }
    if (tid < 2 * NW) ((unsigned long long*)sm.supW)[tid] = 0ull;
    __syncthreads();

    int nsel = 0, prevN = 0;
    bool done = false;
    for (int i = 0; i < NBATCH && !done; ++i) {
        const int p = i & 1;
        if (wav == 0) {
            const bool vC = (keyC >> 32) != 0;
            // delta-check cur vs last resolve's accepts [prevN, nsel)
            int sup = 0;
            for (int j = prevN; j < nsel; ++j)
                sup |= iou_sup(boxC, aC, sm.selbox[j], sm.selA[j]);
            unsigned long long Ed = __ballot(sup);
            unsigned long long V = __ballot(vC);
            // combine the 15 full-check ballots (written last iteration)
            unsigned long long Ef = (lane < NW - 1) ? sm.supW[p][lane + 1] : 0ull;
            #pragma unroll
            for (int d = 1; d < NW; d <<= 1) Ef |= __shfl_xor(Ef, d);
            Ef = __shfl(Ef, 0);
            // resolve with on-demand victim masks: 1 wave-IoU per accept
            uint64_t alive = ~(Ef | Ed | ~V);
            uint64_t accm = 0;
            int cnt = nsel;
            while (alive && cnt < SELCAP) {
                int t = __ffsll((unsigned long long)alive) - 1;
                accm |= 1ull << t;
                cnt++;
                float4 tb;
                tb.x = __shfl(boxC.x, t); tb.y = __shfl(boxC.y, t);
                tb.z = __shfl(boxC.z, t); tb.w = __shfl(boxC.w, t);
                float ta = __shfl(aC, t);
                unsigned long long vict = __ballot(iou_sup(tb, ta, boxC, aC));
                alive &= ~vict;              // self-IoU also clears bit t
                alive &= ~(1ull << t);
            }
            if ((accm >> lane) & 1ull) {
                int pos = nsel + __popcll(accm & ((1ull << lane) - 1ull));
                sm.selbox[pos] = boxC;
                sm.selA[pos] = aC;
                sm.selkey[pos] = keyC;
            }
            if (lane == 0) {
                sm.nselshare = cnt;
                sm.prevNshare = nsel;
                sm.doneflag = (cnt >= SELCAP) || (V != ~0ull);
            }
        } else {
            // chunked early-exit full-check of batch i+1 vs [0..nsel):
            // wave handles candidate c (staged in cbox), lanes = accepted boxes
            unsigned long long sb = 0;
            for (int c = wav - 1; c < 64; c += NW - 1) {
                float4 cb = sm.cbox[p ^ 1][c];
                float ca = sm.carea[p ^ 1][c];
                if (!(ca > 0.0f)) continue;          // invalid: wave-uniform skip
                bool supc = false;
                for (int j0 = 0; j0 < nsel && !supc; j0 += 64) {
                    int j = j0 + lane;
                    int hit = (j < nsel) ? iou_sup(cb, ca, sm.selbox[j], sm.selA[j]) : 0;
                    supc = __ballot(hit) != 0ull;    // wave-uniform early exit
                }
                if (supc) sb |= 1ull << c;
            }
            if (lane == 0) sm.supW[p ^ 1][wav] = sb;
        }
        // all waves: prefetch batch i+2; wave1 stages it into cbox[p]
        int f0 = (i + 2) * 64;
        uint64_t key2 = (f0 < KPAD) ? sm.keys[f0 + lane] : 0;
        float4 box2 = load_box(img, boxoff, key2);
        float a2 = box_area(box2);
        if (wav == 1) { sm.cbox[p][lane] = box2; sm.carea[p][lane] = a2; }
        __syncthreads();  // publish accepts, counters, supW, cbox
        nsel = sm.nselshare;
        prevN = sm.prevNshare;
        done = sm.doneflag != 0;
        keyC = keyN; boxC = boxN; aC = aN;
        keyN = key2; boxN = box2; aN = a2;
    }

    // ---- phase 7: emit ranks [0,256) (all topk reads); zeros past nsel ----
    float* out0 = rows + (size_t)task * MAXOUT * 7;
    for (int r = tid; r < EMITN; r += THREADS) {
        float* o = out0 + (size_t)r * 7;
        if (r < nsel) {
            uint64_t key = sm.selkey[r];
            uint32_t i = 0xFFFFFFFFu - (uint32_t)key;
            float4 bx = sm.selbox[r];
            o[0] = (float)(cm1 + 1);
            o[1] = __uint_as_float((uint32_t)(key >> 32));
            o[2] = bx.x;
            o[3] = bx.y;
            o[4] = bx.z;
            o[5] = bx.w;
            o[6] = img[(size_t)i * LASTD + (LASTD - 1)];
        } else {
            #pragma unroll
            for (int q = 0; q < 7; ++q) o[q] = 0.0f;
        }
    }
}

// One block per image: top-200 by (conf desc, flat idx asc) over 20*400 rows.
// Per-class lists are already sorted desc; top-200 never needs within-class
// rank >= 256, so: 32 lists x 256 keys, 5 rounds of pairwise bitonic top-256
// merges (max-combine + 8 merge stages), then gather the first 200 rows.
// Flat index keeps the reference's list*400+r encoding for exact tie order.
__global__ __launch_bounds__(THREADS) void topk_per_image(const float* __restrict__ rows,
                                                          float* __restrict__ out) {
    __shared__ uint64_t K[8192];
    const int b = blockIdx.x;
    const int tid = threadIdx.x;
    const float* rb = rows + (size_t)b * (NCM1 * MAXOUT) * 7;

    for (int xx = tid; xx < 8192; xx += THREADS) {
        int list = xx >> 8, r = xx & 255;
        uint64_t k = 0;
        if (list < NCM1) {
            int flat = list * MAXOUT + r;
            float conf = rb[(size_t)flat * 7 + 1];
            k = ((uint64_t)__float_as_uint(conf) << 32) |
                (uint32_t)(0xFFFFFFFFu - (uint32_t)flat);
        }
        K[xx] = k;
    }
    __syncthreads();

    for (int round = 0; round < 5; ++round) {
        int npairs = 16 >> round;
        int sep = 256 << round;
        for (int w = tid; w < npairs * 256; w += THREADS) {
            int p = w >> 8, t = w & 255;
            int A = p * 2 * sep;
            uint64_t a = K[A + t];
            uint64_t c = K[A + sep + 255 - t];
            K[A + t] = a > c ? a : c;
        }
        __syncthreads();
        for (int j = 128; j >= 1; j >>= 1) {
            for (int w = tid; w < npairs * 128; w += THREADS) {
                int p = w >> 7, q = w & 127;
                int t = ((q & ~(j - 1)) << 1) | (q & (j - 1));
                int A = p * 2 * sep;
                uint64_t x0 = K[A + t];
                uint64_t x1 = K[A + t + j];
                if (x0 < x1) { K[A + t] = x1; K[A + t + j] = x0; }
            }
            __syncthreads();
        }
    }

    if (tid < TOPK) {
        uint64_t key = K[tid];
        uint32_t flat = 0xFFFFFFFFu - (uint32_t)key;
        const float* src = rb + (size_t)flat * 7;
        float* o = out + ((size_t)b * TOPK + tid) * 7;
        #pragma unroll
        for (int q = 0; q < 7; ++q) o[q] = src[q];
    }
}

extern "C" void kernel_launch(void* const* d_in, const int* in_sizes, int n_in,
                              void* d_out, int out_size, void* d_ws, size_t ws_size,
                              hipStream_t stream) {
    const float* yp = (const float*)d_in[0];
    float* rows = (float*)d_ws;  // NTASK*400*7 floats = 1.792 MB scratch
    float* out = (float*)d_out;

    hipLaunchKernelGGL(nms_per_class, dim3(NTASK), dim3(THREADS), 0, stream, yp, rows);
    hipLaunchKernelGGL(topk_per_image, dim3(NB), dim3(THREADS), 0, stream, rows, out);
}

// Round 11
// 67.941 us; speedup vs baseline: 1.2086x; 1.2086x over previous
//
#include <hip/hip_runtime.h>
#include <cstdint>

#define NB 8
#define NBOX 8732
#define NCL 21
#define NCM1 20
#define LASTD 102
#define CONF_TH 0.5f
#define IOU_TH 0.45f
#define TOPK 200
#define MAXOUT 400     // reference row pitch (flat tie-break encoding)
#define SELCAP 200     // provably sufficient accept cap (== TOPK, r7 proof)
#define EMITN 256      // topk reads within-class ranks [0,256) only
#define NTASK (NB * NCM1)
#define THREADS 1024
#define NW 16
#define NIT 9          // ceil(8732/1024)
#define NBIN 2048
#define KPAD 8768      // 64*137 >= NBOX: counting-sorted keys always fit
#define NBATCH (KPAD / 64)

// Exact equivalence (proven): uni>0 && RN_f32(inter/uni) > 0.45f
//   <=>  (double)inter > MIDD*(double)uni   for our operand domain.
// MIDD = double(0.45f) + 2^-26 (midpoint above 0.45f; 0.45f mantissa even so
// midpoint rounds to 0.45f, not >). 25-bit x 24-bit f64 product is exact.
// uni>0 guard removable: no division; valid-valid pairs have uni>=max area>0;
// pairs with a zero (invalid) box give inter==0 -> false. No NaN path.
#define MIDD ((double)IOU_TH + 0x1p-26)

struct SM {
    float4 selbox[SELCAP];        // 3.2 KB
    float selA[SELCAP];           // 0.8 KB
    uint64_t selkey[SELCAP];      // 1.6 KB
    uint64_t keys[KPAD];          // 70.1 KB
    uint64_t smask[2][64];        // 1 KB: suppressor-major intra-batch masks
    unsigned long long supW[2][NW];  // per-wave ext ballots (fullcheck+delta)
    int hist[NBIN];               // 8 KB
    int binstart[NBIN];           // 8 KB
    int wavetot[NW];
    int Mshare, nselshare, prevNshare, doneflag;
};  // ~93 KB

// IoU(>0.45): explicit RN ops + exact f64-product compare, bit-matching the
// host fp32 reference. Symmetric in (a,b).
__device__ __forceinline__ int iou_sup(float4 a, float aA, float4 b, float bA) {
    float x1 = fmaxf(a.x, b.x), y1 = fmaxf(a.y, b.y);
    float x2 = fminf(a.z, b.z), y2 = fminf(a.w, b.w);
    float iw = fmaxf(__fsub_rn(x2, x1), 0.0f);
    float ih = fmaxf(__fsub_rn(y2, y1), 0.0f);
    float inter = __fmul_rn(iw, ih);
    float uni = __fsub_rn(__fadd_rn(aA, bA), inter);
    return (double)inter > MIDD * (double)uni;
}

__device__ __forceinline__ float4 load_box(const float* __restrict__ img,
                                           int boxoff, uint64_t key) {
    if ((key >> 32) == 0) return make_float4(0.f, 0.f, 0.f, 0.f);
    uint32_t i = 0xFFFFFFFFu - (uint32_t)key;
    const float* bp = img + (size_t)i * LASTD + boxoff;
    return make_float4(bp[0], bp[1], bp[2], bp[3]);
}

__device__ __forceinline__ float box_area(float4 b) {
    return __fmul_rn(__fsub_rn(b.z, b.x), __fsub_rn(b.w, b.y));
}

// One block per (image, class): 2048-bin counting sort of all conf>0.5
// candidates into exact (score desc, idx asc) order, then the round-8
// two-barrier pipelined greedy scan with ext-gated suppressor masks folded
// into the full-check phase. Exactly replicates the reference's 400-step
// argmax+suppress loop; SELCAP=200 is output-equivalent (r7 proof).
__global__ __launch_bounds__(THREADS) void nms_per_class(const float* __restrict__ yp,
                                                         float* __restrict__ rows) {
    __shared__ SM sm;
    const int task = blockIdx.x;
    const int b = task / NCM1;
    const int cm1 = task % NCM1;
    const int tid = threadIdx.x;
    const int lane = tid & 63;
    const int wav = tid >> 6;
    const float* img = yp + (size_t)b * NBOX * LASTD;
    const int boxoff = NCL + 4 * cm1;

    // ---- phase 1: conf column loads (all 9 in flight) ----
    float confs[NIT];
    #pragma unroll
    for (int it = 0; it < NIT; ++it) {
        int idx = it * THREADS + tid;
        confs[it] = (idx < NBOX) ? img[(size_t)idx * LASTD + (1 + cm1)] : 0.0f;
    }
    sm.hist[tid] = 0; sm.hist[tid + THREADS] = 0;
    __syncthreads();

    // ---- phase 2: 2048-bin histogram (top 11 mantissa bits, conf in (0.5,1)) --
    #pragma unroll
    for (int it = 0; it < NIT; ++it) {
        int idx = it * THREADS + tid;
        if (idx < NBOX && confs[it] > CONF_TH) {
            int bin = (int)((__float_as_uint(confs[it]) - 0x3F000000u) >> 12);
            atomicAdd(&sm.hist[bin], 1);
        }
    }
    __syncthreads();

    // ---- phase 3: descending bin bases via suffix-sum over bin pairs ----
    int h0 = sm.hist[2 * tid], h1 = sm.hist[2 * tid + 1];
    int x = h0 + h1;
    int s = x;
    #pragma unroll
    for (int d = 1; d <= 32; d <<= 1) {
        int y = __shfl_down(s, d);
        if (lane + d < 64) s += y;
    }
    if (lane == 0) sm.wavetot[wav] = s;
    __syncthreads();
    int cross = 0;
    #pragma unroll
    for (int w = 0; w < NW; ++w)
        if (w > wav) cross += sm.wavetot[w];
    int Safter = cross + s - x;               // keys in bins strictly above
    sm.binstart[2 * tid + 1] = Safter;        // higher bin (higher score) first
    sm.binstart[2 * tid] = Safter + h1;
    if (tid == 0) sm.Mshare = cross + s;
    sm.hist[2 * tid] = 0; sm.hist[2 * tid + 1] = 0;  // reuse as scatter ctr
    __syncthreads();

    // ---- phase 4: scatter keys to bin regions ----
    #pragma unroll
    for (int it = 0; it < NIT; ++it) {
        int idx = it * THREADS + tid;
        if (idx < NBOX && confs[it] > CONF_TH) {
            uint32_t bits = __float_as_uint(confs[it]);
            int bin = (int)((bits - 0x3F000000u) >> 12);
            int slot = sm.binstart[bin] + atomicAdd(&sm.hist[bin], 1);
            sm.keys[slot] = ((uint64_t)bits << 32) |
                            (uint32_t)(0xFFFFFFFFu - (uint32_t)idx);
        }
    }
    __syncthreads();
    const int M = sm.Mshare;
    for (int m = M + tid; m < KPAD; m += THREADS) sm.keys[m] = 0;
    // ---- phase 5: per-bin insertion sort (2 bins/thread, ~2 keys/bin) ----
    for (int f = tid; f < NBIN; f += THREADS) {
        int s0 = sm.binstart[f], h = sm.hist[f];
        for (int i2 = 1; i2 < h; ++i2) {
            uint64_t key = sm.keys[s0 + i2];
            int j = i2 - 1;
            while (j >= 0 && sm.keys[s0 + j] < key) {
                sm.keys[s0 + j + 1] = sm.keys[s0 + j];
                --j;
            }
            sm.keys[s0 + j + 1] = key;
        }
    }
    __syncthreads();

    // ---- phase 6: two-barrier pipelined greedy scan ----
    // Invariant (round-8, proven): entering iter i (parity p), supW[p] holds
    // cur's ext ballots vs accepted[0..N_{i-2}) (fullcheck at iter i-1) and
    // delta(i) adds [N_{i-2}..N_{i-1}); smask[p] holds cur's suppressor-major
    // intra-batch masks (ext-gated: rows of fullcheck-dead candidates are 0 —
    // never consulted since those candidates are in E at resolve).
    uint64_t keyC = sm.keys[lane];
    uint64_t keyN = sm.keys[64 + lane];
    float4 boxC = load_box(img, boxoff, keyC);
    float4 boxN = load_box(img, boxoff, keyN);
    float aC = box_area(boxC), aN = box_area(boxN);
    // prologue: smask[0] ungated (16-way split), zero supW[0..1]
    #pragma unroll
    for (int tt = 0; tt < 4; ++tt) {
        int c = wav + tt * NW;
        float4 cb;
        cb.x = __shfl(boxC.x, c); cb.y = __shfl(boxC.y, c);
        cb.z = __shfl(boxC.z, c); cb.w = __shfl(boxC.w, c);
        float ca = __shfl(aC, c);
        uint64_t row = 0;
        if (ca > 0.0f)   // wave-uniform
            row = __ballot(lane < c && iou_sup(cb, ca, boxC, aC));
        if (lane == 0) sm.smask[0][c] = row;
    }
    if (tid < 2 * NW) ((unsigned long long*)sm.supW)[tid] = 0ull;
    __syncthreads();

    int nsel = 0, prevN = 0;
    bool done = false;
    for (int i = 0; i < NBATCH && !done; ++i) {
        const int p = i & 1;
        const bool vC = (keyC >> 32) != 0;
        // A (all waves, split): delta-check cur vs accepts [prevN, nsel)
        {
            int sup = 0;
            for (int j = prevN + wav; j < nsel; j += NW)
                sup |= iou_sup(boxC, aC, sm.selbox[j], sm.selA[j]);
            unsigned long long bal = __ballot(vC && sup);
            if (lane == 0 && bal) atomicOr(&sm.supW[p][wav], bal);
        }
        // prefetch batch i+2 into registers
        int f0 = (i + 2) * 64;
        uint64_t key2 = (f0 < KPAD) ? sm.keys[f0 + lane] : 0;
        float4 box2 = load_box(img, boxoff, key2);
        float a2 = box_area(box2);
        __syncthreads();  // [1] supW[p] complete; snapshot nsel
        const int nselPre = nsel;
        if (wav == 0) {
            // resolve cur with precomputed ext-gated smask
            unsigned long long V = __ballot(vC);
            unsigned long long E = (lane < NW) ? sm.supW[p][lane] : 0ull;
            #pragma unroll
            for (int d = 1; d < NW; d <<= 1) E |= __shfl_xor(E, d);
            E = __shfl(E, 0);
            if (lane < NW) sm.supW[p][lane] = 0ull;   // recycle for batch i+2
            uint64_t smc = sm.smask[p][lane];          // suppressors of lane
            uint64_t alive = ~(E | ~V);
            uint64_t accm = 0;
            int cnt = nsel;
            while (alive && cnt < SELCAP) {
                int t = __ffsll((unsigned long long)alive) - 1;
                uint64_t bit = 1ull << t;
                accm |= bit;
                cnt++;
                unsigned long long kill = __ballot((smc >> t) & 1ull);
                alive &= ~(kill | bit);
            }
            if ((accm >> lane) & 1ull) {
                int pos = nsel + __popcll(accm & ((1ull << lane) - 1ull));
                sm.selbox[pos] = boxC;
                sm.selA[pos] = aC;
                sm.selkey[pos] = keyC;
            }
            if (lane == 0) {
                sm.nselshare = cnt;
                sm.prevNshare = nsel;
                sm.doneflag = (cnt >= SELCAP) || (V != ~0ull);
            }
        } else {
            // full-check of batch i+1 vs [0..nselPre) + ext-gated smask.
            // Wave handles candidate c; box broadcast from boxN registers.
            unsigned long long sb = 0;
            for (int c = wav - 1; c < 64; c += NW - 1) {
                float4 cb;
                cb.x = __shfl(boxN.x, c); cb.y = __shfl(boxN.y, c);
                cb.z = __shfl(boxN.z, c); cb.w = __shfl(boxN.w, c);
                float ca = __shfl(aN, c);
                if (!(ca > 0.0f)) {                   // invalid: wave-uniform
                    if (lane == 0) sm.smask[p ^ 1][c] = 0;
                    continue;
                }
                bool supc = false;
                for (int j0 = 0; j0 < nselPre && !supc; j0 += 64) {
                    int j = j0 + lane;
                    int hit = (j < nselPre) ?
                        iou_sup(cb, ca, sm.selbox[j], sm.selA[j]) : 0;
                    supc = __ballot(hit) != 0ull;     // wave-uniform early exit
                }
                uint64_t row = 0;
                if (supc) {
                    sb |= 1ull << c;                  // row never consulted
                } else {
                    row = __ballot(lane < c && iou_sup(cb, ca, boxN, aN));
                }
                if (lane == 0) sm.smask[p ^ 1][c] = row;
            }
            if (lane == 0) sm.supW[p ^ 1][wav] = sb;  // slot was zeroed
        }
        __syncthreads();  // [2] accepts, counters, smask, supW published
        nsel = sm.nselshare;
        prevN = sm.prevNshare;
        done = sm.doneflag != 0;
        keyC = keyN; boxC = boxN; aC = aN;
        keyN = key2; boxN = box2; aN = a2;
    }

    // ---- phase 7: emit ranks [0,256) (all topk reads); zeros past nsel ----
    float* out0 = rows + (size_t)task * MAXOUT * 7;
    for (int r = tid; r < EMITN; r += THREADS) {
        float* o = out0 + (size_t)r * 7;
        if (r < nsel) {
            uint64_t key = sm.selkey[r];
            uint32_t i = 0xFFFFFFFFu - (uint32_t)key;
            float4 bx = sm.selbox[r];
            o[0] = (float)(cm1 + 1);
            o[1] = __uint_as_float((uint32_t)(key >> 32));
            o[2] = bx.x;
            o[3] = bx.y;
            o[4] = bx.z;
            o[5] = bx.w;
            o[6] = img[(size_t)i * LASTD + (LASTD - 1)];
        } else {
            #pragma unroll
            for (int q = 0; q < 7; ++q) o[q] = 0.0f;
        }
    }
}

// One block per image: top-200 by (conf desc, flat idx asc) over 20*400 rows.
// Per-class lists are already sorted desc; top-200 never needs within-class
// rank >= 256, so: 32 lists x 256 keys, 5 rounds of pairwise bitonic top-256
// merges (max-combine + 8 merge stages), then gather the first 200 rows.
// Flat index keeps the reference's list*400+r encoding for exact tie order.
__global__ __launch_bounds__(THREADS) void topk_per_image(const float* __restrict__ rows,
                                                          float* __restrict__ out) {
    __shared__ uint64_t K[8192];
    const int b = blockIdx.x;
    const int tid = threadIdx.x;
    const float* rb = rows + (size_t)b * (NCM1 * MAXOUT) * 7;

    for (int xx = tid; xx < 8192; xx += THREADS) {
        int list = xx >> 8, r = xx & 255;
        uint64_t k = 0;
        if (list < NCM1) {
            int flat = list * MAXOUT + r;
            float conf = rb[(size_t)flat * 7 + 1];
            k = ((uint64_t)__float_as_uint(conf) << 32) |
                (uint32_t)(0xFFFFFFFFu - (uint32_t)flat);
        }
        K[xx] = k;
    }
    __syncthreads();

    for (int round = 0; round < 5; ++round) {
        int npairs = 16 >> round;
        int sep = 256 << round;
        for (int w = tid; w < npairs * 256; w += THREADS) {
            int p = w >> 8, t = w & 255;
            int A = p * 2 * sep;
            uint64_t a = K[A + t];
            uint64_t c = K[A + sep + 255 - t];
            K[A + t] = a > c ? a : c;
        }
        __syncthreads();
        for (int j = 128; j >= 1; j >>= 1) {
            for (int w = tid; w < npairs * 128; w += THREADS) {
                int p = w >> 7, q = w & 127;
                int t = ((q & ~(j - 1)) << 1) | (q & (j - 1));
                int A = p * 2 * sep;
                uint64_t x0 = K[A + t];
                uint64_t x1 = K[A + t + j];
                if (x0 < x1) { K[A + t] = x1; K[A + t + j] = x0; }
            }
            __syncthreads();
        }
    }

    if (tid < TOPK) {
        uint64_t key = K[tid];
        uint32_t flat = 0xFFFFFFFFu - (uint32_t)key;
        const float* src = rb + (size_t)flat * 7;
        float* o = out + ((size_t)b * TOPK + tid) * 7;
        #pragma unroll
        for (int q = 0; q < 7; ++q) o[q] = src[q];
    }
}

extern "C" void kernel_launch(void* const* d_in, const int* in_sizes, int n_in,
                              void* d_out, int out_size, void* d_ws, size_t ws_size,
                              hipStream_t stream) {
    const float* yp = (const float*)d_in[0];
    float* rows = (float*)d_ws;  // NTASK*400*7 floats = 1.792 MB scratch
    float* out = (float*)d_out;

    hipLaunchKernelGGL(nms_per_class, dim3(NTASK), dim3(THREADS), 0, stream, yp, rows);
    hipLaunchKernelGGL(topk_per_image, dim3(NB), dim3(THREADS), 0, stream, rows, out);
}

// Round 12
// 67.568 us; speedup vs baseline: 1.2153x; 1.0055x over previous
//
#include <hip/hip_runtime.h>
#include <cstdint>

#define NB 8
#define NBOX 8732
#define NCL 21
#define NCM1 20
#define LASTD 102
#define CONF_TH 0.5f
#define IOU_TH 0.45f
#define TOPK 200
#define MAXOUT 400     // reference row pitch (flat tie-break encoding)
#define SELCAP 200     // provably sufficient accept cap (== TOPK, r7 proof)
#define EMITN 256      // topk reads within-class ranks [0,256) only
#define NTASK (NB * NCM1)
#define THREADS 1024
#define NW 16
#define NIT 9          // ceil(8732/1024)
#define NBIN 2048
#define KPAD 8768      // 64*137 >= NBOX: counting-sorted keys always fit
#define NBATCH (KPAD / 64)

// Exact equivalence (proven): uni>0 && RN_f32(inter/uni) > 0.45f
//   <=>  (double)inter > MIDD*(double)uni   for our operand domain.
// MIDD = double(0.45f) + 2^-26 (midpoint above 0.45f; 0.45f mantissa even so
// midpoint rounds to 0.45f, not >). 25-bit x 24-bit f64 product is exact.
// uni>0 guard removable: no division; valid-valid pairs have uni>=max area>0;
// pairs with a zero (invalid) box give inter==0 -> false. No NaN path.
#define MIDD ((double)IOU_TH + 0x1p-26)

struct SM {
    float4 selbox[SELCAP];        // 3.2 KB
    float selA[SELCAP];           // 0.8 KB
    uint64_t selkey[SELCAP];      // 1.6 KB
    uint64_t keys[KPAD];          // 70.1 KB
    uint64_t smask[2][64];        // 1 KB: suppressor-major intra-batch masks
    unsigned long long supW[2][NW];  // per-wave ext ballots (fullcheck+delta)
    int hist[NBIN];               // 8 KB
    int binstart[NBIN];           // 8 KB
    int wavetot[NW];
    int Mshare, nselshare, prevNshare, doneflag;
};  // ~93 KB

// IoU(>0.45): explicit RN ops + exact f64-product compare, bit-matching the
// host fp32 reference. Symmetric in (a,b).
__device__ __forceinline__ int iou_sup(float4 a, float aA, float4 b, float bA) {
    float x1 = fmaxf(a.x, b.x), y1 = fmaxf(a.y, b.y);
    float x2 = fminf(a.z, b.z), y2 = fminf(a.w, b.w);
    float iw = fmaxf(__fsub_rn(x2, x1), 0.0f);
    float ih = fmaxf(__fsub_rn(y2, y1), 0.0f);
    float inter = __fmul_rn(iw, ih);
    float uni = __fsub_rn(__fadd_rn(aA, bA), inter);
    return (double)inter > MIDD * (double)uni;
}

__device__ __forceinline__ float4 load_box(const float* __restrict__ img,
                                           int boxoff, uint64_t key) {
    if ((key >> 32) == 0) return make_float4(0.f, 0.f, 0.f, 0.f);
    uint32_t i = 0xFFFFFFFFu - (uint32_t)key;
    const float* bp = img + (size_t)i * LASTD + boxoff;
    return make_float4(bp[0], bp[1], bp[2], bp[3]);
}

__device__ __forceinline__ float box_area(float4 b) {
    return __fmul_rn(__fsub_rn(b.z, b.x), __fsub_rn(b.w, b.y));
}

// One block per (image, class): 2048-bin counting sort of all conf>0.5
// candidates into exact (score desc, idx asc) order, then the two-barrier
// pipelined greedy scan with a chunk-major full-check (one LDS load per
// chunk serves all of a wave's candidates). Exactly replicates the
// reference's argmax+suppress loop; SELCAP=200 is output-equivalent (r7).
__global__ __launch_bounds__(THREADS) void nms_per_class(const float* __restrict__ yp,
                                                         float* __restrict__ rows) {
    __shared__ SM sm;
    const int task = blockIdx.x;
    const int b = task / NCM1;
    const int cm1 = task % NCM1;
    const int tid = threadIdx.x;
    const int lane = tid & 63;
    const int wav = tid >> 6;
    const float* img = yp + (size_t)b * NBOX * LASTD;
    const int boxoff = NCL + 4 * cm1;

    // ---- phase 1: conf column loads (all 9 in flight) ----
    float confs[NIT];
    #pragma unroll
    for (int it = 0; it < NIT; ++it) {
        int idx = it * THREADS + tid;
        confs[it] = (idx < NBOX) ? img[(size_t)idx * LASTD + (1 + cm1)] : 0.0f;
    }
    sm.hist[tid] = 0; sm.hist[tid + THREADS] = 0;
    __syncthreads();

    // ---- phase 2: 2048-bin histogram (top 11 mantissa bits, conf in (0.5,1)) --
    #pragma unroll
    for (int it = 0; it < NIT; ++it) {
        int idx = it * THREADS + tid;
        if (idx < NBOX && confs[it] > CONF_TH) {
            int bin = (int)((__float_as_uint(confs[it]) - 0x3F000000u) >> 12);
            atomicAdd(&sm.hist[bin], 1);
        }
    }
    __syncthreads();

    // ---- phase 3: descending bin bases via suffix-sum over bin pairs ----
    int h0 = sm.hist[2 * tid], h1 = sm.hist[2 * tid + 1];
    int x = h0 + h1;
    int s = x;
    #pragma unroll
    for (int d = 1; d <= 32; d <<= 1) {
        int y = __shfl_down(s, d);
        if (lane + d < 64) s += y;
    }
    if (lane == 0) sm.wavetot[wav] = s;
    __syncthreads();
    int cross = 0;
    #pragma unroll
    for (int w = 0; w < NW; ++w)
        if (w > wav) cross += sm.wavetot[w];
    int Safter = cross + s - x;               // keys in bins strictly above
    sm.binstart[2 * tid + 1] = Safter;        // higher bin (higher score) first
    sm.binstart[2 * tid] = Safter + h1;
    if (tid == 0) sm.Mshare = cross + s;
    sm.hist[2 * tid] = 0; sm.hist[2 * tid + 1] = 0;  // reuse as scatter ctr
    __syncthreads();

    // ---- phase 4: scatter keys to bin regions ----
    #pragma unroll
    for (int it = 0; it < NIT; ++it) {
        int idx = it * THREADS + tid;
        if (idx < NBOX && confs[it] > CONF_TH) {
            uint32_t bits = __float_as_uint(confs[it]);
            int bin = (int)((bits - 0x3F000000u) >> 12);
            int slot = sm.binstart[bin] + atomicAdd(&sm.hist[bin], 1);
            sm.keys[slot] = ((uint64_t)bits << 32) |
                            (uint32_t)(0xFFFFFFFFu - (uint32_t)idx);
        }
    }
    __syncthreads();
    const int M = sm.Mshare;
    for (int m = M + tid; m < KPAD; m += THREADS) sm.keys[m] = 0;
    // ---- phase 5: per-bin insertion sort (2 bins/thread, ~2 keys/bin) ----
    for (int f = tid; f < NBIN; f += THREADS) {
        int s0 = sm.binstart[f], h = sm.hist[f];
        for (int i2 = 1; i2 < h; ++i2) {
            uint64_t key = sm.keys[s0 + i2];
            int j = i2 - 1;
            while (j >= 0 && sm.keys[s0 + j] < key) {
                sm.keys[s0 + j + 1] = sm.keys[s0 + j];
                --j;
            }
            sm.keys[s0 + j + 1] = key;
        }
    }
    __syncthreads();

    // ---- phase 6: two-barrier pipelined greedy scan ----
    // Invariant (round-8, proven): entering iter i (parity p), supW[p] holds
    // cur's ext ballots vs accepted[0..N_{i-2}) (fullcheck at iter i-1) and
    // delta(i) adds [N_{i-2}..N_{i-1}); smask[p] holds cur's suppressor-major
    // intra-batch masks (ext-gated: rows of dead candidates are stale/0 —
    // never consulted since those candidates are in E|~V at resolve).
    uint64_t keyC = sm.keys[lane];
    uint64_t keyN = sm.keys[64 + lane];
    float4 boxC = load_box(img, boxoff, keyC);
    float4 boxN = load_box(img, boxoff, keyN);
    float aC = box_area(boxC), aN = box_area(boxN);
    // prologue: smask[0] ungated (16-way split), zero supW[0..1]
    #pragma unroll
    for (int tt = 0; tt < 4; ++tt) {
        int c = wav + tt * NW;
        float4 cb;
        cb.x = __shfl(boxC.x, c); cb.y = __shfl(boxC.y, c);
        cb.z = __shfl(boxC.z, c); cb.w = __shfl(boxC.w, c);
        float ca = __shfl(aC, c);
        uint64_t row = 0;
        if (ca > 0.0f)   // wave-uniform
            row = __ballot(lane < c && iou_sup(cb, ca, boxC, aC));
        if (lane == 0) sm.smask[0][c] = row;
    }
    if (tid < 2 * NW) ((unsigned long long*)sm.supW)[tid] = 0ull;
    __syncthreads();

    int nsel = 0, prevN = 0;
    bool done = false;
    for (int i = 0; i < NBATCH && !done; ++i) {
        const int p = i & 1;
        const bool vC = (keyC >> 32) != 0;
        // A (all waves, split): delta-check cur vs accepts [prevN, nsel)
        {
            int sup = 0;
            for (int j = prevN + wav; j < nsel; j += NW)
                sup |= iou_sup(boxC, aC, sm.selbox[j], sm.selA[j]);
            unsigned long long bal = __ballot(vC && sup);
            if (lane == 0 && bal) atomicOr(&sm.supW[p][wav], bal);
        }
        // prefetch batch i+2 into registers
        int f0 = (i + 2) * 64;
        uint64_t key2 = (f0 < KPAD) ? sm.keys[f0 + lane] : 0;
        float4 box2 = load_box(img, boxoff, key2);
        float a2 = box_area(box2);
        __syncthreads();  // [1] supW[p] complete; snapshot nsel
        const int nselPre = nsel;
        if (wav == 0) {
            // resolve cur with precomputed ext-gated smask
            unsigned long long V = __ballot(vC);
            unsigned long long E = (lane < NW) ? sm.supW[p][lane] : 0ull;
            #pragma unroll
            for (int d = 1; d < NW; d <<= 1) E |= __shfl_xor(E, d);
            E = __shfl(E, 0);
            if (lane < NW) sm.supW[p][lane] = 0ull;   // recycle for batch i+2
            uint64_t smc = sm.smask[p][lane];          // suppressors of lane
            uint64_t alive = ~(E | ~V);
            uint64_t accm = 0;
            int cnt = nsel;
            while (alive && cnt < SELCAP) {
                int t = __ffsll((unsigned long long)alive) - 1;
                uint64_t bit = 1ull << t;
                accm |= bit;
                cnt++;
                unsigned long long kill = __ballot((smc >> t) & 1ull);
                alive &= ~(kill | bit);
            }
            if ((accm >> lane) & 1ull) {
                int pos = nsel + __popcll(accm & ((1ull << lane) - 1ull));
                sm.selbox[pos] = boxC;
                sm.selA[pos] = aC;
                sm.selkey[pos] = keyC;
            }
            if (lane == 0) {
                sm.nselshare = cnt;
                sm.prevNshare = nsel;
                sm.doneflag = (cnt >= SELCAP) || (V != ~0ull);
            }
        } else {
            // chunk-major full-check of batch i+1 vs [0..nselPre).
            // Wave owns candidates c = (wav-1) + 15k; boxes pre-broadcast to
            // wave-uniform registers. One LDS load pair per 64-chunk serves
            // all still-alive candidates; per-candidate ballots prune amask.
            float4 cb[5];
            float ca[5];
            unsigned amask = 0;    // wave-uniform: alive candidate slots
            #pragma unroll
            for (int k = 0; k < 5; ++k) {
                int c = (wav - 1) + k * (NW - 1);
                float4 t4 = make_float4(0.f, 0.f, 0.f, 0.f);
                float tA = 0.0f;
                if (c < 64) {
                    t4.x = __shfl(boxN.x, c); t4.y = __shfl(boxN.y, c);
                    t4.z = __shfl(boxN.z, c); t4.w = __shfl(boxN.w, c);
                    tA = __shfl(aN, c);
                }
                cb[k] = t4; ca[k] = tA;
                if (c < 64 && tA > 0.0f) amask |= 1u << k;
            }
            unsigned long long sb = 0;
            for (int j0 = 0; j0 < nselPre && amask; j0 += 64) {
                int j = j0 + lane;
                bool jv = j < nselPre;
                float4 sbx = sm.selbox[jv ? j : 0];
                float sA = sm.selA[jv ? j : 0];
                #pragma unroll
                for (int k = 0; k < 5; ++k) {
                    if (!((amask >> k) & 1u)) continue;   // wave-uniform
                    int hit = jv && iou_sup(cb[k], ca[k], sbx, sA);
                    if (__ballot(hit)) {
                        amask &= ~(1u << k);
                        sb |= 1ull << ((wav - 1) + k * (NW - 1));
                    }
                }
            }
            // smask rows only for surviving candidates (dead rows unused)
            #pragma unroll
            for (int k = 0; k < 5; ++k) {
                if (!((amask >> k) & 1u)) continue;
                int c = (wav - 1) + k * (NW - 1);
                uint64_t row = __ballot(lane < c && iou_sup(cb[k], ca[k], boxN, aN));
                if (lane == 0) sm.smask[p ^ 1][c] = row;
            }
            if (lane == 0) sm.supW[p ^ 1][wav] = sb;
        }
        __syncthreads();  // [2] accepts, counters, smask, supW published
        nsel = sm.nselshare;
        prevN = sm.prevNshare;
        done = sm.doneflag != 0;
        keyC = keyN; boxC = boxN; aC = aN;
        keyN = key2; boxN = box2; aN = a2;
    }

    // ---- phase 7: emit ranks [0,256) (all topk reads); zeros past nsel ----
    float* out0 = rows + (size_t)task * MAXOUT * 7;
    for (int r = tid; r < EMITN; r += THREADS) {
        float* o = out0 + (size_t)r * 7;
        if (r < nsel) {
            uint64_t key = sm.selkey[r];
            uint32_t i = 0xFFFFFFFFu - (uint32_t)key;
            float4 bx = sm.selbox[r];
            o[0] = (float)(cm1 + 1);
            o[1] = __uint_as_float((uint32_t)(key >> 32));
            o[2] = bx.x;
            o[3] = bx.y;
            o[4] = bx.z;
            o[5] = bx.w;
            o[6] = img[(size_t)i * LASTD + (LASTD - 1)];
        } else {
            #pragma unroll
            for (int q = 0; q < 7; ++q) o[q] = 0.0f;
        }
    }
}

// One block per image: top-200 by (conf desc, flat idx asc) over 20*400 rows.
// Per-class lists are already sorted desc; top-200 never needs within-class
// rank >= 256, so: 32 lists x 256 keys, 5 rounds of pairwise bitonic top-256
// merges (max-combine + 8 merge stages), then gather the first 200 rows.
// Flat index keeps the reference's list*400+r encoding for exact tie order.
__global__ __launch_bounds__(THREADS) void topk_per_image(const float* __restrict__ rows,
                                                          float* __restrict__ out) {
    __shared__ uint64_t K[8192];
    const int b = blockIdx.x;
    const int tid = threadIdx.x;
    const float* rb = rows + (size_t)b * (NCM1 * MAXOUT) * 7;

    for (int xx = tid; xx < 8192; xx += THREADS) {
        int list = xx >> 8, r = xx & 255;
        uint64_t k = 0;
        if (list < NCM1) {
            int flat = list * MAXOUT + r;
            float conf = rb[(size_t)flat * 7 + 1];
            k = ((uint64_t)__float_as_uint(conf) << 32) |
                (uint32_t)(0xFFFFFFFFu - (uint32_t)flat);
        }
        K[xx] = k;
    }
    __syncthreads();

    for (int round = 0; round < 5; ++round) {
        int npairs = 16 >> round;
        int sep = 256 << round;
        for (int w = tid; w < npairs * 256; w += THREADS) {
            int p = w >> 8, t = w & 255;
            int A = p * 2 * sep;
            uint64_t a = K[A + t];
            uint64_t c = K[A + sep + 255 - t];
            K[A + t] = a > c ? a : c;
        }
        __syncthreads();
        for (int j = 128; j >= 1; j >>= 1) {
            for (int w = tid; w < npairs * 128; w += THREADS) {
                int p = w >> 7, q = w & 127;
                int t = ((q & ~(j - 1)) << 1) | (q & (j - 1));
                int A = p * 2 * sep;
                uint64_t x0 = K[A + t];
                uint64_t x1 = K[A + t + j];
                if (x0 < x1) { K[A + t] = x1; K[A + t + j] = x0; }
            }
            __syncthreads();
        }
    }

    if (tid < TOPK) {
        uint64_t key = K[tid];
        uint32_t flat = 0xFFFFFFFFu - (uint32_t)key;
        const float* src = rb + (size_t)flat * 7;
        float* o = out + ((size_t)b * TOPK + tid) * 7;
        #pragma unroll
        for (int q = 0; q < 7; ++q) o[q] = src[q];
    }
}

extern "C" void kernel_launch(void* const* d_in, const int* in_sizes, int n_in,
                              void* d_out, int out_size, void* d_ws, size_t ws_size,
                              hipStream_t stream) {
    const float* yp = (const float*)d_in[0];
    float* rows = (float*)d_ws;  // NTASK*400*7 floats = 1.792 MB scratch
    float* out = (float*)d_out;

    hipLaunchKernelGGL(nms_per_class, dim3(NTASK), dim3(THREADS), 0, stream, yp, rows);
    hipLaunchKernelGGL(topk_per_image, dim3(NB), dim3(THREADS), 0, stream, rows, out);
}

// Round 13
// 66.543 us; speedup vs baseline: 1.2340x; 1.0154x over previous
//
#include <hip/hip_runtime.h>
#include <cstdint>

#define NB 8
#define NBOX 8732
#define NCL 21
#define NCM1 20
#define LASTD 102
#define CONF_TH 0.5f
#define IOU_TH 0.45f
#define TOPK 200
#define MAXOUT 400     // reference row pitch (flat tie-break encoding)
#define SELCAP 200     // provably sufficient accept cap (== TOPK, r7 proof)
#define EMITN 256      // topk reads within-class ranks [0,256) only
#define NTASK (NB * NCM1)
#define THREADS 1024
#define NW 16
#define NIT 9          // ceil(8732/1024)
#define NBIN 2048
#define KPAD 8832      // 128*69 >= NBOX: counting-sorted keys always fit
#define NPAIR (KPAD / 128)

// Exact equivalence (proven): uni>0 && RN_f32(inter/uni) > 0.45f
//   <=>  (double)inter > MIDD*(double)uni   for our operand domain.
// MIDD = double(0.45f) + 2^-26 (midpoint above 0.45f; 0.45f mantissa even so
// midpoint rounds to 0.45f, not >). 25-bit x 24-bit f64 product is exact.
// uni>0 guard removable: no division; valid-valid pairs have uni>=max area>0;
// pairs with a zero (invalid) box give inter==0 -> false. No NaN path.
#define MIDD ((double)IOU_TH + 0x1p-26)

struct SM {
    float4 selbox[SELCAP];        // 3.2 KB
    float selA[SELCAP];           // 0.8 KB
    uint64_t selkey[SELCAP];      // 1.6 KB
    uint64_t keys[KPAD];          // 70.7 KB
    uint64_t smA[2][64];          // A-vs-A suppressor-major rows
    uint64_t smB[2][64];          // B-vs-B rows
    uint64_t smBA[2][64];         // B-cand row over A-cands (cross-batch)
    unsigned long long extA[2], extB[2];  // ext ballots (atomicOr targets)
    int hist[NBIN];               // 8 KB
    int binstart[NBIN];           // 8 KB
    int wavetot[NW];
    int Mshare, nselshare, prevNshare, doneflag;
};  // ~96 KB

// IoU(>0.45): explicit RN ops + exact f64-product compare, bit-matching the
// host fp32 reference. Symmetric in (a,b).
__device__ __forceinline__ int iou_sup(float4 a, float aA, float4 b, float bA) {
    float x1 = fmaxf(a.x, b.x), y1 = fmaxf(a.y, b.y);
    float x2 = fminf(a.z, b.z), y2 = fminf(a.w, b.w);
    float iw = fmaxf(__fsub_rn(x2, x1), 0.0f);
    float ih = fmaxf(__fsub_rn(y2, y1), 0.0f);
    float inter = __fmul_rn(iw, ih);
    float uni = __fsub_rn(__fadd_rn(aA, bA), inter);
    return (double)inter > MIDD * (double)uni;
}

__device__ __forceinline__ float4 load_box(const float* __restrict__ img,
                                           int boxoff, uint64_t key) {
    if ((key >> 32) == 0) return make_float4(0.f, 0.f, 0.f, 0.f);
    uint32_t i = 0xFFFFFFFFu - (uint32_t)key;
    const float* bp = img + (size_t)i * LASTD + boxoff;
    return make_float4(bp[0], bp[1], bp[2], bp[3]);
}

__device__ __forceinline__ float box_area(float4 b) {
    return __fmul_rn(__fsub_rn(b.z, b.x), __fsub_rn(b.w, b.y));
}

__device__ __forceinline__ float4 shfl_box(float4 b, int c) {
    float4 r;
    r.x = __shfl(b.x, c); r.y = __shfl(b.y, c);
    r.z = __shfl(b.z, c); r.w = __shfl(b.w, c);
    return r;
}

// One block per (image, class): 2048-bin counting sort of all conf>0.5
// candidates into exact (score desc, idx asc) order, then a pipelined greedy
// scan over 128-candidate batch-pairs: wave0 resolves pair m (A then B, with
// precomputed cross-batch masks) while waves 1-15 full-check pair m+1 vs the
// accepted snapshot. Exactly replicates the reference argmax+suppress loop;
// SELCAP=200 is output-equivalent (r7 proof).
__global__ __launch_bounds__(THREADS) void nms_per_class(const float* __restrict__ yp,
                                                         float* __restrict__ rows) {
    __shared__ SM sm;
    const int task = blockIdx.x;
    const int b = task / NCM1;
    const int cm1 = task % NCM1;
    const int tid = threadIdx.x;
    const int lane = tid & 63;
    const int wav = tid >> 6;
    const float* img = yp + (size_t)b * NBOX * LASTD;
    const int boxoff = NCL + 4 * cm1;

    // ---- phase 1: conf column loads (all 9 in flight) ----
    float confs[NIT];
    #pragma unroll
    for (int it = 0; it < NIT; ++it) {
        int idx = it * THREADS + tid;
        confs[it] = (idx < NBOX) ? img[(size_t)idx * LASTD + (1 + cm1)] : 0.0f;
    }
    sm.hist[tid] = 0; sm.hist[tid + THREADS] = 0;
    __syncthreads();

    // ---- phase 2: 2048-bin histogram (top 11 mantissa bits, conf in (0.5,1)) --
    #pragma unroll
    for (int it = 0; it < NIT; ++it) {
        int idx = it * THREADS + tid;
        if (idx < NBOX && confs[it] > CONF_TH) {
            int bin = (int)((__float_as_uint(confs[it]) - 0x3F000000u) >> 12);
            atomicAdd(&sm.hist[bin], 1);
        }
    }
    __syncthreads();

    // ---- phase 3: descending bin bases via suffix-sum over bin pairs ----
    int h0 = sm.hist[2 * tid], h1 = sm.hist[2 * tid + 1];
    int x = h0 + h1;
    int s = x;
    #pragma unroll
    for (int d = 1; d <= 32; d <<= 1) {
        int y = __shfl_down(s, d);
        if (lane + d < 64) s += y;
    }
    if (lane == 0) sm.wavetot[wav] = s;
    __syncthreads();
    int cross = 0;
    #pragma unroll
    for (int w = 0; w < NW; ++w)
        if (w > wav) cross += sm.wavetot[w];
    int Safter = cross + s - x;               // keys in bins strictly above
    sm.binstart[2 * tid + 1] = Safter;        // higher bin (higher score) first
    sm.binstart[2 * tid] = Safter + h1;
    if (tid == 0) sm.Mshare = cross + s;
    sm.hist[2 * tid] = 0; sm.hist[2 * tid + 1] = 0;  // reuse as scatter ctr
    __syncthreads();

    // ---- phase 4: scatter keys to bin regions ----
    #pragma unroll
    for (int it = 0; it < NIT; ++it) {
        int idx = it * THREADS + tid;
        if (idx < NBOX && confs[it] > CONF_TH) {
            uint32_t bits = __float_as_uint(confs[it]);
            int bin = (int)((bits - 0x3F000000u) >> 12);
            int slot = sm.binstart[bin] + atomicAdd(&sm.hist[bin], 1);
            sm.keys[slot] = ((uint64_t)bits << 32) |
                            (uint32_t)(0xFFFFFFFFu - (uint32_t)idx);
        }
    }
    __syncthreads();
    const int M = sm.Mshare;
    for (int m = M + tid; m < KPAD; m += THREADS) sm.keys[m] = 0;
    // ---- phase 5: per-bin insertion sort (2 bins/thread, ~2 keys/bin) ----
    for (int f = tid; f < NBIN; f += THREADS) {
        int s0 = sm.binstart[f], h = sm.hist[f];
        for (int i2 = 1; i2 < h; ++i2) {
            uint64_t key = sm.keys[s0 + i2];
            int j = i2 - 1;
            while (j >= 0 && sm.keys[s0 + j] < key) {
                sm.keys[s0 + j + 1] = sm.keys[s0 + j];
                --j;
            }
            sm.keys[s0 + j + 1] = key;
        }
    }
    __syncthreads();

    // ---- phase 6: batch-pair pipelined greedy scan ----
    // Iteration m (parity p): delta-checks pair m vs accepts [prevN..nsel);
    // extA/extB[p] already hold pair-m ext vs [0..prevN) (fullcheck at m-1);
    // smA/smB/smBA[p] hold pair-m masks. Wave0 resolves A then B (cross-batch
    // via rBA & accm_A); waves 1-15 fullcheck pair m+1 vs [0..nselPre).
    uint64_t keyA = sm.keys[lane],        keyB = sm.keys[64 + lane];
    uint64_t keyA2 = sm.keys[128 + lane], keyB2 = sm.keys[192 + lane];
    float4 boxA = load_box(img, boxoff, keyA);
    float4 boxB = load_box(img, boxoff, keyB);
    float4 boxA2 = load_box(img, boxoff, keyA2);
    float4 boxB2 = load_box(img, boxoff, keyB2);
    float aA = box_area(boxA), aB = box_area(boxB);
    float aA2 = box_area(boxA2), aB2 = box_area(boxB2);
    // prologue: ungated masks for pair 0 (16-way split), zero ext words
    #pragma unroll
    for (int tt = 0; tt < 4; ++tt) {
        int c = wav + tt * NW;
        float4 cbA = shfl_box(boxA, c);
        float caA = __shfl(aA, c);
        uint64_t rA = 0;
        if (caA > 0.0f)
            rA = __ballot(lane < c && iou_sup(cbA, caA, boxA, aA));
        if (lane == 0) sm.smA[0][c] = rA;
        float4 cbB = shfl_box(boxB, c);
        float caB = __shfl(aB, c);
        uint64_t rB = 0, rBA = 0;
        if (caB > 0.0f) {
            rB = __ballot(lane < c && iou_sup(cbB, caB, boxB, aB));
            rBA = __ballot(iou_sup(cbB, caB, boxA, aA));
        }
        if (lane == 0) { sm.smB[0][c] = rB; sm.smBA[0][c] = rBA; }
    }
    if (tid == 0) {
        sm.extA[0] = 0; sm.extB[0] = 0; sm.extA[1] = 0; sm.extB[1] = 0;
    }
    __syncthreads();

    int nsel = 0, prevN = 0;
    bool done = false;
    for (int m = 0; m < NPAIR && !done; ++m) {
        const int p = m & 1;
        // delta: all waves split accepts [prevN..nsel), test A and B
        {
            int supA = 0, supB = 0;
            for (int j = prevN + wav; j < nsel; j += NW) {
                float4 sbx = sm.selbox[j];
                float sA = sm.selA[j];
                supA |= iou_sup(boxA, aA, sbx, sA);
                supB |= iou_sup(boxB, aB, sbx, sA);
            }
            unsigned long long balA = __ballot(supA);
            unsigned long long balB = __ballot(supB);
            if (lane == 0) {
                if (balA) atomicOr(&sm.extA[p], balA);
                if (balB) atomicOr(&sm.extB[p], balB);
            }
        }
        // prefetch pair m+2
        int f0 = (m + 2) * 128;
        uint64_t keyA3 = (f0 < KPAD) ? sm.keys[f0 + lane] : 0;
        uint64_t keyB3 = (f0 < KPAD) ? sm.keys[f0 + 64 + lane] : 0;
        float4 boxA3 = load_box(img, boxoff, keyA3);
        float4 boxB3 = load_box(img, boxoff, keyB3);
        float aA3 = box_area(boxA3), aB3 = box_area(boxB3);
        __syncthreads();  // [1] ext[p] complete; snapshot nsel
        const int nselPre = nsel;
        if (wav == 0) {
            // resolve pair m: A then B (sequential greedy, exact order)
            unsigned long long VA = __ballot((keyA >> 32) != 0);
            unsigned long long VB = __ballot((keyB >> 32) != 0);
            unsigned long long EA = sm.extA[p];
            unsigned long long EB = sm.extB[p];
            if (lane == 0) { sm.extA[p] = 0ull; sm.extB[p] = 0ull; }
            uint64_t smcA = sm.smA[p][lane];
            uint64_t smcB = sm.smB[p][lane];
            uint64_t rBA  = sm.smBA[p][lane];
            uint64_t alive = ~(EA | ~VA);
            uint64_t accmA = 0;
            int cnt = nsel;
            while (alive && cnt < SELCAP) {
                int t = __ffsll((unsigned long long)alive) - 1;
                uint64_t bit = 1ull << t;
                accmA |= bit;
                cnt++;
                unsigned long long kill = __ballot((smcA >> t) & 1ull);
                alive &= ~(kill | bit);
            }
            const int cntA = cnt;
            unsigned long long exB = __ballot((rBA & accmA) != 0ull);
            alive = ~(EB | ~VB | exB);
            uint64_t accmB = 0;
            while (alive && cnt < SELCAP) {
                int t = __ffsll((unsigned long long)alive) - 1;
                uint64_t bit = 1ull << t;
                accmB |= bit;
                cnt++;
                unsigned long long kill = __ballot((smcB >> t) & 1ull);
                alive &= ~(kill | bit);
            }
            if ((accmA >> lane) & 1ull) {
                int pos = nsel + __popcll(accmA & ((1ull << lane) - 1ull));
                sm.selbox[pos] = boxA; sm.selA[pos] = aA; sm.selkey[pos] = keyA;
            }
            if ((accmB >> lane) & 1ull) {
                int pos = cntA + __popcll(accmB & ((1ull << lane) - 1ull));
                sm.selbox[pos] = boxB; sm.selA[pos] = aB; sm.selkey[pos] = keyB;
            }
            if (lane == 0) {
                sm.nselshare = cnt;
                sm.prevNshare = nsel;
                sm.doneflag = (cnt >= SELCAP) || (VB != ~0ull);
            }
        } else {
            // fullcheck pair m+1 (boxA2/boxB2) vs [0..nselPre); two passes.
            // Wave owns slots c = (wav-1) + k*15; chunk loads serve all slots.
            #pragma unroll
            for (int pass = 0; pass < 2; ++pass) {
                float4 bx = pass ? boxB2 : boxA2;
                float ax = pass ? aB2 : aA2;
                float4 cb0, cb1, cb2, cb3, cb4;
                float ca0, ca1, ca2, ca3, ca4;
                int c0 = wav - 1, c1 = c0 + 15, c2 = c0 + 30, c3 = c0 + 45,
                    c4 = c0 + 60;
                cb0 = shfl_box(bx, c0); ca0 = __shfl(ax, c0);
                cb1 = shfl_box(bx, c1); ca1 = __shfl(ax, c1);
                cb2 = shfl_box(bx, c2); ca2 = __shfl(ax, c2);
                cb3 = shfl_box(bx, c3); ca3 = __shfl(ax, c3);
                cb4 = shfl_box(bx, c4 & 63); ca4 = __shfl(ax, c4 & 63);
                int t0 = 0, t1 = 0, t2 = 0, t3 = 0, t4 = 0;
                for (int j0 = 0; j0 < nselPre; j0 += 64) {
                    int j = j0 + lane;
                    int jv = j < nselPre;
                    float4 sbx = sm.selbox[jv ? j : 0];
                    float sA = sm.selA[jv ? j : 0];
                    t0 |= jv & iou_sup(cb0, ca0, sbx, sA);
                    t1 |= jv & iou_sup(cb1, ca1, sbx, sA);
                    t2 |= jv & iou_sup(cb2, ca2, sbx, sA);
                    t3 |= jv & iou_sup(cb3, ca3, sbx, sA);
                    t4 |= jv & iou_sup(cb4, ca4, sbx, sA);
                }
                unsigned long long sb = 0;
                #pragma unroll
                for (int k = 0; k < 5; ++k) {
                    int c = c0 + k * 15;
                    float4 cb = k == 0 ? cb0 : k == 1 ? cb1 : k == 2 ? cb2
                               : k == 3 ? cb3 : cb4;
                    float ca = k == 0 ? ca0 : k == 1 ? ca1 : k == 2 ? ca2
                              : k == 3 ? ca3 : ca4;
                    int hk = k == 0 ? t0 : k == 1 ? t1 : k == 2 ? t2
                            : k == 3 ? t3 : t4;
                    if (c < 64 && ca > 0.0f) {        // wave-uniform
                        unsigned long long bal = __ballot(hk);
                        if (bal) {
                            sb |= 1ull << c;
                        } else if (pass == 0) {
                            uint64_t row = __ballot(lane < c &&
                                iou_sup(cb, ca, boxA2, aA2));
                            if (lane == 0) sm.smA[p ^ 1][c] = row;
                        } else {
                            uint64_t row = __ballot(lane < c &&
                                iou_sup(cb, ca, boxB2, aB2));
                            uint64_t rba = __ballot(iou_sup(cb, ca, boxA2, aA2));
                            if (lane == 0) {
                                sm.smB[p ^ 1][c] = row;
                                sm.smBA[p ^ 1][c] = rba;
                            }
                        }
                    }
                }
                if (lane == 0 && sb) {
                    if (pass == 0) atomicOr(&sm.extA[p ^ 1], sb);
                    else           atomicOr(&sm.extB[p ^ 1], sb);
                }
            }
        }
        __syncthreads();  // [2] accepts, counters, masks, ext published
        nsel = sm.nselshare;
        prevN = sm.prevNshare;
        done = sm.doneflag != 0;
        keyA = keyA2; boxA = boxA2; aA = aA2;
        keyB = keyB2; boxB = boxB2; aB = aB2;
        keyA2 = keyA3; boxA2 = boxA3; aA2 = aA3;
        keyB2 = keyB3; boxB2 = boxB3; aB2 = aB3;
    }

    // ---- phase 7: emit ranks [0,256) (all topk reads); zeros past nsel ----
    float* out0 = rows + (size_t)task * MAXOUT * 7;
    for (int r = tid; r < EMITN; r += THREADS) {
        float* o = out0 + (size_t)r * 7;
        if (r < nsel) {
            uint64_t key = sm.selkey[r];
            uint32_t i = 0xFFFFFFFFu - (uint32_t)key;
            float4 bx = sm.selbox[r];
            o[0] = (float)(cm1 + 1);
            o[1] = __uint_as_float((uint32_t)(key >> 32));
            o[2] = bx.x;
            o[3] = bx.y;
            o[4] = bx.z;
            o[5] = bx.w;
            o[6] = img[(size_t)i * LASTD + (LASTD - 1)];
        } else {
            #pragma unroll
            for (int q = 0; q < 7; ++q) o[q] = 0.0f;
        }
    }
}

// One block per image: top-200 by (conf desc, flat idx asc) over 20*400 rows.
// Per-class lists are already sorted desc; top-200 never needs within-class
// rank >= 256, so: 32 lists x 256 keys, 5 rounds of pairwise bitonic top-256
// merges (max-combine + 8 merge stages), then gather the first 200 rows.
// Flat index keeps the reference's list*400+r encoding for exact tie order.
__global__ __launch_bounds__(THREADS) void topk_per_image(const float* __restrict__ rows,
                                                          float* __restrict__ out) {
    __shared__ uint64_t K[8192];
    const int b = blockIdx.x;
    const int tid = threadIdx.x;
    const float* rb = rows + (size_t)b * (NCM1 * MAXOUT) * 7;

    for (int xx = tid; xx < 8192; xx += THREADS) {
        int list = xx >> 8, r = xx & 255;
        uint64_t k = 0;
        if (list < NCM1) {
            int flat = list * MAXOUT + r;
            float conf = rb[(size_t)flat * 7 + 1];
            k = ((uint64_t)__float_as_uint(conf) << 32) |
                (uint32_t)(0xFFFFFFFFu - (uint32_t)flat);
        }
        K[xx] = k;
    }
    __syncthreads();

    for (int round = 0; round < 5; ++round) {
        int npairs = 16 >> round;
        int sep = 256 << round;
        for (int w = tid; w < npairs * 256; w += THREADS) {
            int p = w >> 8, t = w & 255;
            int A = p * 2 * sep;
            uint64_t a = K[A + t];
            uint64_t c = K[A + sep + 255 - t];
            K[A + t] = a > c ? a : c;
        }
        __syncthreads();
        for (int j = 128; j >= 1; j >>= 1) {
            for (int w = tid; w < npairs * 128; w += THREADS) {
                int p = w >> 7, q = w & 127;
                int t = ((q & ~(j - 1)) << 1) | (q & (j - 1));
                int A = p * 2 * sep;
                uint64_t x0 = K[A + t];
                uint64_t x1 = K[A + t + j];
                if (x0 < x1) { K[A + t] = x1; K[A + t + j] = x0; }
            }
            __syncthreads();
        }
    }

    if (tid < TOPK) {
        uint64_t key = K[tid];
        uint32_t flat = 0xFFFFFFFFu - (uint32_t)key;
        const float* src = rb + (size_t)flat * 7;
        float* o = out + ((size_t)b * TOPK + tid) * 7;
        #pragma unroll
        for (int q = 0; q < 7; ++q) o[q] = src[q];
    }
}

extern "C" void kernel_launch(void* const* d_in, const int* in_sizes, int n_in,
                              void* d_out, int out_size, void* d_ws, size_t ws_size,
                              hipStream_t stream) {
    const float* yp = (const float*)d_in[0];
    float* rows = (float*)d_ws;  // NTASK*400*7 floats = 1.792 MB scratch
    float* out = (float*)d_out;

    hipLaunchKernelGGL(nms_per_class, dim3(NTASK), dim3(THREADS), 0, stream, yp, rows);
    hipLaunchKernelGGL(topk_per_image, dim3(NB), dim3(THREADS), 0, stream, rows, out);
}